// Round 6
// baseline (1317.528 us; speedup 1.0000x reference)
//
#include <hip/hip_runtime.h>
#include <hip/hip_bf16.h>

typedef __attribute__((ext_vector_type(4))) float f32x4;
typedef __attribute__((ext_vector_type(4))) unsigned int u32x4;
typedef __attribute__((ext_vector_type(8))) __bf16 bf16x8;

#define DEV static __device__ __forceinline__

DEV unsigned short f2bf(float f) {
  unsigned u = __builtin_bit_cast(unsigned, f);
  u += 0x7fffu + ((u >> 16) & 1u);
  return (unsigned short)(u >> 16);
}
DEV float bf2f(unsigned short b) {
  return __builtin_bit_cast(float, ((unsigned)b) << 16);
}
DEV unsigned pk2(float a, float b) {
  return (unsigned)f2bf(a) | ((unsigned)f2bf(b) << 16);
}
DEV unsigned cvtpk(float lo, float hi) {
  unsigned r;
  asm("v_cvt_pk_bf16_f32 %0, %1, %2" : "=v"(r) : "v"(lo), "v"(hi));
  return r;
}
DEV float fexp2(float x) {
  float r;
  asm("v_exp_f32 %0, %1" : "=v"(r) : "v"(x));
  return r;
}
DEV f32x4 mfma16(u32x4 a, u32x4 b, f32x4 c) {
  return __builtin_amdgcn_mfma_f32_16x16x32_bf16(
      __builtin_bit_cast(bf16x8, a), __builtin_bit_cast(bf16x8, b), c, 0, 0, 0);
}
DEV float ssq8(u32x4 c) {
  float s = 0.f;
#pragma unroll
  for (int e = 0; e < 4; e++) {
    float lo = __builtin_bit_cast(float, c[e] << 16);
    float hi = __builtin_bit_cast(float, c[e] & 0xffff0000u);
    s += lo * lo + hi * hi;
  }
  return s;
}
DEV void gload16(const unsigned short* g, unsigned short* l) {
  __builtin_amdgcn_global_load_lds(
      (const __attribute__((address_space(1))) unsigned int*)g,
      (__attribute__((address_space(3))) unsigned int*)l, 16, 0, 0);
}

// ---------------------------------------------------------------------------
// bf16 GEMM: C = A[M][K] * B[N][K]^T + bias. EPI: 0 = bf16, 1 = gelu->bf16
// 128x128 tile, BK=32, TRIPLE-buffered (48 KB LDS), 2-deep prefetch with
// counted s_waitcnt vmcnt(4) + raw s_barrier (T3/T4: loads stay in flight
// across barriers; only the final iteration drains to 0).
// global_load_lds with granule-XOR swizzle (pre-swizzled source / swizzled
// read, both-sides involution). XCD owns an M-chunk, N fastest (L2 reuse).
// Requires K%32==0, N%128==0, grid%8==0, (grid/8)%nblocks==0.
// ---------------------------------------------------------------------------
template <int EPI>
__global__ __launch_bounds__(256) void gemm_lds(
    const unsigned short* __restrict__ A, const unsigned short* __restrict__ B,
    const float* __restrict__ bias, unsigned short* __restrict__ C,
    int N, int K, int nblocks) {
  __shared__ __align__(16) unsigned short As[3][128 * 32];
  __shared__ __align__(16) unsigned short Bs[3][128 * 32];
  const int bid = blockIdx.x;
  const int mchunk = (gridDim.x >> 3) / nblocks;
  const int xcd = bid & 7, idx = bid >> 3;
  const int nb = idx % nblocks, ml = idx / nblocks;
  const int m0 = (xcd * mchunk + ml) * 128, n0 = nb * 128;
  const int tid = threadIdx.x, w = tid >> 6, l = tid & 63;

  // staging: wave w, load i covers rows [w*32+i*16, +16), 4 granules/row
  const int rs = l >> 2;
  const int gs = ((l & 3) ^ ((l >> 3) & 3)) * 8;  // pre-swizzled src granule
  const unsigned short* ag = A + (size_t)(m0 + w * 32 + rs) * K + gs;
  const unsigned short* bg = B + (size_t)(n0 + w * 32 + rs) * K + gs;
  const int seg = w * 1024;  // wave-uniform dest elems; HW adds lane*16B

  const int wm = (w >> 1) << 6, wn = (w & 1) << 6;
  const int lr = l & 15, lg = l >> 4;
  const int gsw = (lg ^ ((lr >> 1) & 3)) * 8;  // swizzled read granule

  const f32x4 z4 = {0.f, 0.f, 0.f, 0.f};
  f32x4 acc[4][4];
#pragma unroll
  for (int i = 0; i < 4; i++)
#pragma unroll
    for (int j = 0; j < 4; j++) acc[i][j] = z4;

  auto stage = [&](int buf, int k0) {
    gload16(ag + k0, &As[buf][seg]);
    gload16(ag + (size_t)16 * K + k0, &As[buf][seg + 512]);
    gload16(bg + k0, &Bs[buf][seg]);
    gload16(bg + (size_t)16 * K + k0, &Bs[buf][seg + 512]);
  };
  auto compute = [&](int buf) {
    u32x4 a[4], b[4];
#pragma unroll
    for (int i = 0; i < 4; i++)
      a[i] = *(const u32x4*)(&As[buf][(wm + i * 16 + lr) * 32 + gsw]);
#pragma unroll
    for (int j = 0; j < 4; j++)
      b[j] = *(const u32x4*)(&Bs[buf][(wn + j * 16 + lr) * 32 + gsw]);
#pragma unroll
    for (int i = 0; i < 4; i++)
#pragma unroll
      for (int j = 0; j < 4; j++) acc[i][j] = mfma16(a[i], b[j], acc[i][j]);
  };

  const int nt = K >> 5;
  stage(0, 0);
  stage(1, 32);
  for (int t = 0; t < nt; ++t) {
    // wait for stage(t) only: stage(t+1)'s 4 loads may stay in flight
    if (t + 1 < nt) {
      asm volatile("s_waitcnt vmcnt(4)" ::: "memory");
    } else {
      asm volatile("s_waitcnt vmcnt(0)" ::: "memory");
    }
    __builtin_amdgcn_s_barrier();
    __builtin_amdgcn_sched_barrier(0);
    if (t + 2 < nt) stage((t + 2) % 3, (t + 2) * 32);  // overlaps compute(t..t+1)
    compute(t % 3);
  }

#pragma unroll
  for (int j = 0; j < 4; j++) {
    int ncol = n0 + wn + j * 16 + lr;
    float bv = bias[ncol];
#pragma unroll
    for (int i = 0; i < 4; i++) {
      int mbase = m0 + wm + i * 16 + lg * 4;
#pragma unroll
      for (int r = 0; r < 4; r++) {
        float v = acc[i][j][r] + bv;
        if (EPI == 1) v = 0.5f * v * (1.0f + erff(v * 0.70710678f));
        C[(size_t)(mbase + r) * N + ncol] = f2bf(v);
      }
    }
  }
}

// ---------------------------------------------------------------------------
// shift + window gather + fp32->bf16
// ---------------------------------------------------------------------------
__global__ __launch_bounds__(256) void gather_cvt(
    const float* __restrict__ x, unsigned short* __restrict__ xb) {
  int wv = threadIdx.x >> 6, l = threadIdx.x & 63;
  int m = blockIdx.x * 4 + wv;
  int w = m >> 6, t = m & 63;
  int b = w >> 6, wy = (w >> 3) & 7, wx = w & 7;
  int oy = (wy * 8 + (t >> 3) + 4) & 63;
  int ox = (wx * 8 + (t & 7) + 4) & 63;
  const float2* src =
      (const float2*)(x + (size_t)((((b << 6) | oy) << 6) | ox) * 384 + l * 6);
  float2 f0 = src[0], f1 = src[1], f2 = src[2];
  unsigned* dst = (unsigned*)(xb + (size_t)m * 384 + l * 6);
  dst[0] = pk2(f0.x, f0.y);
  dst[1] = pk2(f1.x, f1.y);
  dst[2] = pk2(f2.x, f2.y);
}

// ---------------------------------------------------------------------------
// Attention: 4 waves/block, wave = one head. Swapped QK^T, in-register
// softmax (exp2 domain, combined bias+mask table), in-register P repack.
// ---------------------------------------------------------------------------
__global__ __launch_bounds__(256, 4) void attn_win(
    const unsigned short* __restrict__ qkv, const float* __restrict__ btab2,
    const float* __restrict__ lscale, unsigned short* __restrict__ aout) {
  __shared__ __align__(16) unsigned short vT[4][32 * 72];
  __shared__ __align__(16) float rnk[4][64];
  const int w = blockIdx.x;
  const int wv = threadIdx.x >> 6, l = threadIdx.x & 63;
  const int h = blockIdx.y * 4 + wv;
  const int lr = l & 15, lg = l >> 4;
  const size_t base = (size_t)w * 64 * 1152 + h * 32;
  const f32x4 z4 = {0.f, 0.f, 0.f, 0.f};

  {
    const u32x4* vp = (const u32x4*)(qkv + base + (size_t)l * 1152 + 768);
#pragma unroll
    for (int c4 = 0; c4 < 4; c4++) {
      u32x4 c = vp[c4];
#pragma unroll
      for (int e = 0; e < 4; e++) {
        vT[wv][(c4 * 8 + e * 2) * 72 + l] = (unsigned short)(c[e] & 0xffffu);
        vT[wv][(c4 * 8 + e * 2 + 1) * 72 + l] = (unsigned short)(c[e] >> 16);
      }
    }
  }
  u32x4 kf[4];
#pragma unroll
  for (int tj = 0; tj < 4; tj++) {
    kf[tj] = *(const u32x4*)(qkv + base + (size_t)(tj * 16 + lr) * 1152 + 384 + lg * 8);
    float s = ssq8(kf[tj]);
    s += __shfl_xor(s, 16, 64);
    s += __shfl_xor(s, 32, 64);
    if (lg == 0) rnk[wv][tj * 16 + lr] = rsqrtf(fmaxf(s, 1e-24f));
  }
  u32x4 qf[4];
  float rnq[4];
#pragma unroll
  for (int ti = 0; ti < 4; ti++) {
    qf[ti] = *(const u32x4*)(qkv + base + (size_t)(ti * 16 + lr) * 1152 + lg * 8);
    float s = ssq8(qf[ti]);
    s += __shfl_xor(s, 16, 64);
    s += __shfl_xor(s, 32, 64);
    rnq[ti] = rsqrtf(fmaxf(s, 1e-24f));
  }
  __syncthreads();

  u32x4 vb[2][2];
#pragma unroll
  for (int kc = 0; kc < 2; kc++)
#pragma unroll
    for (int tj2 = 0; tj2 < 2; tj2++)
      vb[kc][tj2] = *(const u32x4*)(&vT[wv][(tj2 * 16 + lr) * 72 + kc * 32 + lg * 8]);

  const float scl2 = expf(fminf(lscale[h], 4.6051702f)) * 1.44269504f;
  const int wt = ((((w >> 3) & 7) == 7) ? 2 : 0) | (((w & 7) == 7) ? 1 : 0);
  const float* tabh = btab2 + (((size_t)wt * 12 + h) << 12);
  const int s0l = lr + ((l & 16) ? 32 : 0);
  const int s1l = s0l + 16;
  const bool hi = (l & 32) != 0;

#pragma unroll
  for (int ti = 0; ti < 4; ti++) {
    f32x4 sv[4];
#pragma unroll
    for (int tj = 0; tj < 4; tj++) sv[tj] = mfma16(kf[tj], qf[ti], z4);
    const float* tab = tabh + ((ti * 16 + lr) << 6);
    const float cb = rnq[ti] * scl2;
    f32x4 val[4];
    float m = -1e30f;
#pragma unroll
    for (int tj = 0; tj < 4; tj++) {
      f32x4 rk4 = *(const f32x4*)(&rnk[wv][tj * 16 + lg * 4]);
      f32x4 t4 = *(const f32x4*)(tab + tj * 16 + lg * 4);
#pragma unroll
      for (int r = 0; r < 4; r++) {
        float v = sv[tj][r] * (cb * rk4[r]) + t4[r];
        val[tj][r] = v;
        m = fmaxf(m, v);
      }
    }
    m = fmaxf(m, __shfl_xor(m, 16, 64));
    m = fmaxf(m, __shfl_xor(m, 32, 64));
    float den = 0.f;
#pragma unroll
    for (int tj = 0; tj < 4; tj++)
#pragma unroll
      for (int r = 0; r < 4; r++) {
        float p = fexp2(val[tj][r] - m);
        val[tj][r] = p;
        den += p;
      }
    den += __shfl_xor(den, 16, 64);
    den += __shfl_xor(den, 32, 64);
    float rden = 1.f / den;
#pragma unroll
    for (int tj = 0; tj < 4; tj++)
#pragma unroll
      for (int r = 0; r < 4; r++) val[tj][r] *= rden;

    f32x4 o[2] = {z4, z4};
#pragma unroll
    for (int kc = 0; kc < 2; kc++) {
      unsigned yA0 = cvtpk(val[2 * kc][0], val[2 * kc][1]);
      unsigned yA1 = cvtpk(val[2 * kc][2], val[2 * kc][3]);
      unsigned yB0 = cvtpk(val[2 * kc + 1][0], val[2 * kc + 1][1]);
      unsigned yB1 = cvtpk(val[2 * kc + 1][2], val[2 * kc + 1][3]);
      unsigned a0 = __shfl((int)yA0, s0l, 64), b0 = __shfl((int)yB0, s0l, 64);
      unsigned a1 = __shfl((int)yA1, s0l, 64), b1 = __shfl((int)yB1, s0l, 64);
      unsigned a2 = __shfl((int)yA0, s1l, 64), b2 = __shfl((int)yB0, s1l, 64);
      unsigned a3 = __shfl((int)yA1, s1l, 64), b3 = __shfl((int)yB1, s1l, 64);
      u32x4 pa = {hi ? b0 : a0, hi ? b1 : a1, hi ? b2 : a2, hi ? b3 : a3};
#pragma unroll
      for (int tj2 = 0; tj2 < 2; tj2++) o[tj2] = mfma16(pa, vb[kc][tj2], o[tj2]);
    }
#pragma unroll
    for (int tj2 = 0; tj2 < 2; tj2++)
#pragma unroll
      for (int r = 0; r < 4; r++)
        aout[(size_t)(w * 64 + ti * 16 + lg * 4 + r) * 384 + h * 32 + tj2 * 16 + lr] =
            f2bf(o[tj2][r]);
  }
}

// ---------------------------------------------------------------------------
// LN1: y1b = bf16(x + LN(proj gathered back))
// ---------------------------------------------------------------------------
__global__ __launch_bounds__(256) void ln1_kernel(
    const unsigned short* __restrict__ projb, const float* __restrict__ x,
    const float* __restrict__ nw, const float* __restrict__ nb,
    unsigned short* __restrict__ y1b) {
  int wv = threadIdx.x >> 6, l = threadIdx.x & 63;
  int n = blockIdx.x * 4 + wv;
  int b = n >> 12, y = (n >> 6) & 63, xx = n & 63;
  int sy = (y + 60) & 63, sx = (xx + 60) & 63;
  int m = ((((b << 6) | ((sy >> 3) << 3) | (sx >> 3)) << 6) |
           ((sy & 7) << 3) | (sx & 7));
  const unsigned* pr = (const unsigned*)(projb + (size_t)m * 384 + l * 6);
  unsigned u0 = pr[0], u1 = pr[1], u2 = pr[2];
  float v[6] = {bf2f((unsigned short)(u0 & 0xffffu)), bf2f((unsigned short)(u0 >> 16)),
                bf2f((unsigned short)(u1 & 0xffffu)), bf2f((unsigned short)(u1 >> 16)),
                bf2f((unsigned short)(u2 & 0xffffu)), bf2f((unsigned short)(u2 >> 16))};
  float sum = 0.f, ssq = 0.f;
#pragma unroll
  for (int c = 0; c < 6; c++) { sum += v[c]; ssq += v[c] * v[c]; }
#pragma unroll
  for (int d = 1; d < 64; d <<= 1) {
    sum += __shfl_xor(sum, d, 64);
    ssq += __shfl_xor(ssq, d, 64);
  }
  float mu = sum * (1.f / 384.f);
  float rstd = rsqrtf(ssq * (1.f / 384.f) - mu * mu + 1e-5f);
  const float2* xr = (const float2*)(x + (size_t)n * 384 + l * 6);
  float2 x0 = xr[0], x1 = xr[1], x2 = xr[2];
  float xv[6] = {x0.x, x0.y, x1.x, x1.y, x2.x, x2.y};
  float o[6];
#pragma unroll
  for (int c = 0; c < 6; c++) {
    int i = l * 6 + c;
    o[c] = xv[c] + (v[c] - mu) * rstd * nw[i] + nb[i];
  }
  unsigned* yb = (unsigned*)(y1b + (size_t)n * 384 + l * 6);
  yb[0] = pk2(o[0], o[1]);
  yb[1] = pk2(o[2], o[3]);
  yb[2] = pk2(o[4], o[5]);
}

// LN2: yout = y1 + LN(h2)   (f32 final output)
__global__ __launch_bounds__(256) void ln2_kernel(
    const unsigned short* __restrict__ y1b, const unsigned short* __restrict__ h2b,
    const float* __restrict__ nw, const float* __restrict__ nb,
    float* __restrict__ yout) {
  int wv = threadIdx.x >> 6, l = threadIdx.x & 63;
  int n = blockIdx.x * 4 + wv;
  const unsigned* hr = (const unsigned*)(h2b + (size_t)n * 384 + l * 6);
  unsigned u0 = hr[0], u1 = hr[1], u2 = hr[2];
  float v[6] = {bf2f((unsigned short)(u0 & 0xffffu)), bf2f((unsigned short)(u0 >> 16)),
                bf2f((unsigned short)(u1 & 0xffffu)), bf2f((unsigned short)(u1 >> 16)),
                bf2f((unsigned short)(u2 & 0xffffu)), bf2f((unsigned short)(u2 >> 16))};
  float sum = 0.f, ssq = 0.f;
#pragma unroll
  for (int c = 0; c < 6; c++) { sum += v[c]; ssq += v[c] * v[c]; }
#pragma unroll
  for (int d = 1; d < 64; d <<= 1) {
    sum += __shfl_xor(sum, d, 64);
    ssq += __shfl_xor(ssq, d, 64);
  }
  float mu = sum * (1.f / 384.f);
  float rstd = rsqrtf(ssq * (1.f / 384.f) - mu * mu + 1e-5f);
  const unsigned* yr = (const unsigned*)(y1b + (size_t)n * 384 + l * 6);
  unsigned y0 = yr[0], y1 = yr[1], y2 = yr[2];
  float yv[6] = {bf2f((unsigned short)(y0 & 0xffffu)), bf2f((unsigned short)(y0 >> 16)),
                 bf2f((unsigned short)(y1 & 0xffffu)), bf2f((unsigned short)(y1 >> 16)),
                 bf2f((unsigned short)(y2 & 0xffffu)), bf2f((unsigned short)(y2 >> 16))};
  float o[6];
#pragma unroll
  for (int c = 0; c < 6; c++) {
    int i = l * 6 + c;
    o[c] = yv[c] + (v[c] - mu) * rstd * nw[i] + nb[i];
  }
  float2* yo = (float2*)(yout + (size_t)n * 384 + l * 6);
  yo[0] = make_float2(o[0], o[1]);
  yo[1] = make_float2(o[2], o[3]);
  yo[2] = make_float2(o[4], o[5]);
}

// combined (bias + mask)*log2e table: btab2[wtype][h][q][k]
__global__ __launch_bounds__(256) void btab2_kernel(
    const float* __restrict__ w1, const float* __restrict__ b1,
    const float* __restrict__ w2, const float* __restrict__ b2,
    float* __restrict__ btab2) {
  int p = blockIdx.x * 256 + threadIdx.x;
  int i = p >> 6, j = p & 63;
  float dy = (float)((i >> 3) - (j >> 3));
  float dx = (float)((i & 7) - (j & 7));
  float r0 = (dy > 0.f ? 1.f : (dy < 0.f ? -1.f : 0.f)) * log1pf(fabsf(dy));
  float r1 = (dx > 0.f ? 1.f : (dx < 0.f ? -1.f : 0.f)) * log1pf(fabsf(dx));
  float acc[12];
#pragma unroll
  for (int hh = 0; hh < 12; hh++) acc[hh] = b2[hh];
  for (int c = 0; c < 384; c++) {
    float hv = w1[c * 2] * r0 + w1[c * 2 + 1] * r1 + b1[c];
    hv = fmaxf(hv, 0.f);
#pragma unroll
    for (int hh = 0; hh < 12; hh++) acc[hh] += hv * w2[hh * 384 + c];
  }
  bool ddy = ((i >> 3) >= 4) != ((j >> 3) >= 4);
  bool ddx = ((i & 7) >= 4) != ((j & 7) >= 4);
  const float L2E = 1.44269504f;
#pragma unroll
  for (int wt = 0; wt < 4; wt++) {
    float mask = ((((wt >> 1) != 0) && ddy) || (((wt & 1) != 0) && ddx)) ? -100.f : 0.f;
#pragma unroll
    for (int hh = 0; hh < 12; hh++)
      btab2[(((size_t)wt * 12 + hh) << 12) + p] = (acc[hh] + mask) * L2E;
  }
}

__global__ __launch_bounds__(256) void cvt_kernel(
    const float* __restrict__ s, unsigned short* __restrict__ d, int n) {
  int i = blockIdx.x * 256 + threadIdx.x;
  if (i < n) d[i] = f2bf(s[i]);
}

// ---------------------------------------------------------------------------
extern "C" void kernel_launch(void* const* d_in, const int* in_sizes, int n_in,
                              void* d_out, int out_size, void* d_ws,
                              size_t ws_size, hipStream_t stream) {
  (void)in_sizes; (void)n_in; (void)out_size; (void)ws_size;
  const float* x      = (const float*)d_in[0];
  const float* qkv_w  = (const float*)d_in[1];
  const float* qkv_b  = (const float*)d_in[2];
  const float* proj_w = (const float*)d_in[3];
  const float* proj_b = (const float*)d_in[4];
  const float* mw1    = (const float*)d_in[5];
  const float* mb1    = (const float*)d_in[6];
  const float* mw2    = (const float*)d_in[7];
  const float* mb2    = (const float*)d_in[8];
  const float* lsc    = (const float*)d_in[9];
  const float* n1w    = (const float*)d_in[10];
  const float* n1b    = (const float*)d_in[11];
  const float* w1     = (const float*)d_in[12];
  const float* b1     = (const float*)d_in[13];
  const float* w2     = (const float*)d_in[14];
  const float* b2     = (const float*)d_in[15];
  const float* n2w    = (const float*)d_in[16];
  const float* n2b    = (const float*)d_in[17];

  char* ws = (char*)d_ws;
  unsigned short* wqb  = (unsigned short*)(ws + 0);
  unsigned short* wpb  = (unsigned short*)(ws + 884736);
  unsigned short* w1b  = (unsigned short*)(ws + 1179648);
  unsigned short* w2b  = (unsigned short*)(ws + 2359296);
  float* btab2         = (float*)(ws + 3538944);             // 786 KB
  unsigned short* xb   = (unsigned short*)(ws + 4718592);    // 100.7 MB
  unsigned short* qkvb = (unsigned short*)(ws + 105381888);  // 302 MB
  unsigned short* att  = (unsigned short*)(ws + 407371776);  // 100.7 MB
  unsigned short* hb   = (unsigned short*)(ws + 508035072);  // 100.7 MB (chunk)
  unsigned short* projb = xb;    // xb dead after QKV GEMM
  unsigned short* y1b   = att;   // att dead after proj GEMM
  unsigned short* h2b   = qkvb;  // qkvb dead after attention
  float* yout = (float*)d_out;

  cvt_kernel<<<dim3(1728), 256, 0, stream>>>(qkv_w, wqb, 442368);
  cvt_kernel<<<dim3(576), 256, 0, stream>>>(proj_w, wpb, 147456);
  cvt_kernel<<<dim3(2304), 256, 0, stream>>>(w1, w1b, 589824);
  cvt_kernel<<<dim3(2304), 256, 0, stream>>>(w2, w2b, 589824);
  btab2_kernel<<<dim3(16), 256, 0, stream>>>(mw1, mb1, mw2, mb2, btab2);
  gather_cvt<<<dim3(32768), 256, 0, stream>>>(x, xb);

  // QKV: 131072 x 1152 x 384
  gemm_lds<0><<<dim3(9216), 256, 0, stream>>>(xb, wqb, qkv_b, qkvb, 1152, 384, 9);
  // attention: 4 heads/block
  attn_win<<<dim3(2048, 3), 256, 0, stream>>>(qkvb, btab2, lsc, att);
  // proj: 131072 x 384 x 384
  gemm_lds<0><<<dim3(3072), 256, 0, stream>>>(att, wpb, proj_b, projb, 384, 384, 3);
  // LN1 + residual (+ ungather) -> bf16 only
  ln1_kernel<<<dim3(32768), 256, 0, stream>>>(projb, x, n1w, n1b, y1b);
  // MLP, 4 chunks of 32768 rows (hb = 100 MB stays L3-resident)
  for (int c = 0; c < 4; c++) {
    const unsigned short* ya = y1b + (size_t)c * 32768 * 384;
    unsigned short* h2c = h2b + (size_t)c * 32768 * 384;
    gemm_lds<1><<<dim3(3072), 256, 0, stream>>>(ya, w1b, b1, hb, 1536, 384, 12);
    gemm_lds<0><<<dim3(768), 256, 0, stream>>>(hb, w2b, b2, h2c, 384, 1536, 3);
  }
  // LN2 + residual -> f32 output
  ln2_kernel<<<dim3(32768), 256, 0, stream>>>(y1b, h2b, n2w, n2b, yout);
}

// Round 7
// 1283.759 us; speedup vs baseline: 1.0263x; 1.0263x over previous
//
#include <hip/hip_runtime.h>
#include <hip/hip_bf16.h>

typedef __attribute__((ext_vector_type(4))) float f32x4;
typedef __attribute__((ext_vector_type(4))) unsigned int u32x4;
typedef __attribute__((ext_vector_type(8))) __bf16 bf16x8;

#define DEV static __device__ __forceinline__

DEV unsigned short f2bf(float f) {
  unsigned u = __builtin_bit_cast(unsigned, f);
  u += 0x7fffu + ((u >> 16) & 1u);
  return (unsigned short)(u >> 16);
}
DEV float bf2f(unsigned short b) {
  return __builtin_bit_cast(float, ((unsigned)b) << 16);
}
DEV unsigned pk2(float a, float b) {
  return (unsigned)f2bf(a) | ((unsigned)f2bf(b) << 16);
}
DEV unsigned cvtpk(float lo, float hi) {
  unsigned r;
  asm("v_cvt_pk_bf16_f32 %0, %1, %2" : "=v"(r) : "v"(lo), "v"(hi));
  return r;
}
DEV float fexp2(float x) {
  float r;
  asm("v_exp_f32 %0, %1" : "=v"(r) : "v"(x));
  return r;
}
DEV f32x4 mfma16(u32x4 a, u32x4 b, f32x4 c) {
  return __builtin_amdgcn_mfma_f32_16x16x32_bf16(
      __builtin_bit_cast(bf16x8, a), __builtin_bit_cast(bf16x8, b), c, 0, 0, 0);
}
DEV float ssq8(u32x4 c) {
  float s = 0.f;
#pragma unroll
  for (int e = 0; e < 4; e++) {
    float lo = __builtin_bit_cast(float, c[e] << 16);
    float hi = __builtin_bit_cast(float, c[e] & 0xffff0000u);
    s += lo * lo + hi * hi;
  }
  return s;
}
DEV void gload16(const unsigned short* g, unsigned short* l) {
  __builtin_amdgcn_global_load_lds(
      (const __attribute__((address_space(1))) unsigned int*)g,
      (__attribute__((address_space(3))) unsigned int*)l, 16, 0, 0);
}

// ---------------------------------------------------------------------------
// bf16 GEMM: C = A[M][K] * B[N][K]^T + bias. EPI: 0 = bf16, 1 = gelu->bf16
// 128x128 tile, BK=32, triple-buffered, counted vmcnt (r6 structure).
// ---------------------------------------------------------------------------
template <int EPI>
__global__ __launch_bounds__(256) void gemm_lds(
    const unsigned short* __restrict__ A, const unsigned short* __restrict__ B,
    const float* __restrict__ bias, unsigned short* __restrict__ C,
    int N, int K, int nblocks) {
  __shared__ __align__(16) unsigned short As[3][128 * 32];
  __shared__ __align__(16) unsigned short Bs[3][128 * 32];
  const int bid = blockIdx.x;
  const int mchunk = (gridDim.x >> 3) / nblocks;
  const int xcd = bid & 7, idx = bid >> 3;
  const int nb = idx % nblocks, ml = idx / nblocks;
  const int m0 = (xcd * mchunk + ml) * 128, n0 = nb * 128;
  const int tid = threadIdx.x, w = tid >> 6, l = tid & 63;

  const int rs = l >> 2;
  const int gs = ((l & 3) ^ ((l >> 3) & 3)) * 8;
  const unsigned short* ag = A + (size_t)(m0 + w * 32 + rs) * K + gs;
  const unsigned short* bg = B + (size_t)(n0 + w * 32 + rs) * K + gs;
  const int seg = w * 1024;

  const int wm = (w >> 1) << 6, wn = (w & 1) << 6;
  const int lr = l & 15, lg = l >> 4;
  const int gsw = (lg ^ ((lr >> 1) & 3)) * 8;

  const f32x4 z4 = {0.f, 0.f, 0.f, 0.f};
  f32x4 acc[4][4];
#pragma unroll
  for (int i = 0; i < 4; i++)
#pragma unroll
    for (int j = 0; j < 4; j++) acc[i][j] = z4;

  auto stage = [&](int buf, int k0) {
    gload16(ag + k0, &As[buf][seg]);
    gload16(ag + (size_t)16 * K + k0, &As[buf][seg + 512]);
    gload16(bg + k0, &Bs[buf][seg]);
    gload16(bg + (size_t)16 * K + k0, &Bs[buf][seg + 512]);
  };
  auto compute = [&](int buf) {
    u32x4 a[4], b[4];
#pragma unroll
    for (int i = 0; i < 4; i++)
      a[i] = *(const u32x4*)(&As[buf][(wm + i * 16 + lr) * 32 + gsw]);
#pragma unroll
    for (int j = 0; j < 4; j++)
      b[j] = *(const u32x4*)(&Bs[buf][(wn + j * 16 + lr) * 32 + gsw]);
#pragma unroll
    for (int i = 0; i < 4; i++)
#pragma unroll
      for (int j = 0; j < 4; j++) acc[i][j] = mfma16(a[i], b[j], acc[i][j]);
  };

  const int nt = K >> 5;
  stage(0, 0);
  stage(1, 32);
  for (int t = 0; t < nt; ++t) {
    if (t + 1 < nt) {
      asm volatile("s_waitcnt vmcnt(4)" ::: "memory");
    } else {
      asm volatile("s_waitcnt vmcnt(0)" ::: "memory");
    }
    __builtin_amdgcn_s_barrier();
    __builtin_amdgcn_sched_barrier(0);
    if (t + 2 < nt) stage((t + 2) % 3, (t + 2) * 32);
    compute(t % 3);
  }

#pragma unroll
  for (int j = 0; j < 4; j++) {
    int ncol = n0 + wn + j * 16 + lr;
    float bv = bias[ncol];
#pragma unroll
    for (int i = 0; i < 4; i++) {
      int mbase = m0 + wm + i * 16 + lg * 4;
#pragma unroll
      for (int r = 0; r < 4; r++) {
        float v = acc[i][j][r] + bv;
        if (EPI == 1) v = 0.5f * v * (1.0f + erff(v * 0.70710678f));
        C[(size_t)(mbase + r) * N + ncol] = f2bf(v);
      }
    }
  }
}

// ---------------------------------------------------------------------------
// Fused GEMM (BN = 384 = full row) + LayerNorm + residual.
// MODE 0 (proj+LN1): out_bf16[n] = bf16(resf[n] + LN(A@B^T + bias)), n = ungather(m)
// MODE 1 (fc2+LN2):  out_f32[m]  = bf16->f32(resb[m]) + LN(A@B^T + bias)
// 512 threads = 8 waves (2M x 4N), wave tile 64x96, BK=32, double-buffered.
// LDS = 64 KB. LN stats via cross-wave LDS partials (aliased onto As[0],
// safe: last compute reads buf 1 since nt is even).
// ---------------------------------------------------------------------------
template <int MODE>
__global__ __launch_bounds__(512) void gemm_ln(
    const unsigned short* __restrict__ A, const unsigned short* __restrict__ Bw,
    const float* __restrict__ bias, const float* __restrict__ resf,
    const unsigned short* __restrict__ resb, const float* __restrict__ nw,
    const float* __restrict__ nb, unsigned short* __restrict__ outb,
    float* __restrict__ outf, int K) {
  __shared__ __align__(16) unsigned short As[2][4096];   // 128 rows x 32
  __shared__ __align__(16) unsigned short Bs[2][12288];  // 384 rows x 32
  const int bid = blockIdx.x;
  const int swz = (bid & 7) * (gridDim.x >> 3) + (bid >> 3);
  const int m0 = swz * 128;
  const int tid = threadIdx.x, w8 = tid >> 6, l = tid & 63;
  const int lr = l & 15, lg = l >> 4;
  const int gsw = (lg ^ ((lr >> 1) & 3)) * 8;
  const int wm2 = (w8 >> 2) * 64;       // 0 or 64
  const int wn4 = w8 & 3;               // n-group: cols wn4*96..+95

  // staging: 32 gload16 per K-step (A rows 0-127 -> g 0..7; B rows 0-383 -> g 8..31)
  const int rs = l >> 2;
  const int gsrc = ((l & 3) ^ ((l >> 3) & 3)) * 8;
  const unsigned short* g_src[4];
  unsigned short* g_dst[4];
  int g_str[4];
#pragma unroll
  for (int i = 0; i < 4; i++) {
    int g = w8 * 4 + i;
    if (g < 8) {
      g_src[i] = A + (size_t)(m0 + g * 16 + rs) * K + gsrc;
      g_dst[i] = &As[0][g * 512];
      g_str[i] = 4096;
    } else {
      g_src[i] = Bw + (size_t)((g - 8) * 16 + rs) * K + gsrc;
      g_dst[i] = &Bs[0][(g - 8) * 512];
      g_str[i] = 12288;
    }
  }
  auto stage = [&](int buf, int k0) {
#pragma unroll
    for (int i = 0; i < 4; i++) gload16(g_src[i] + k0, g_dst[i] + buf * g_str[i]);
  };

  const f32x4 z4 = {0.f, 0.f, 0.f, 0.f};
  f32x4 acc[4][6];
#pragma unroll
  for (int i = 0; i < 4; i++)
#pragma unroll
    for (int j = 0; j < 6; j++) acc[i][j] = z4;

  auto compute = [&](int buf) {
    u32x4 a[4], b[6];
#pragma unroll
    for (int i = 0; i < 4; i++)
      a[i] = *(const u32x4*)(&As[buf][(wm2 + i * 16 + lr) * 32 + gsw]);
#pragma unroll
    for (int j = 0; j < 6; j++)
      b[j] = *(const u32x4*)(&Bs[buf][(wn4 * 96 + j * 16 + lr) * 32 + gsw]);
#pragma unroll
    for (int i = 0; i < 4; i++)
#pragma unroll
      for (int j = 0; j < 6; j++) acc[i][j] = mfma16(a[i], b[j], acc[i][j]);
  };

  const int nt = K >> 5;  // even (12 or 48)
  stage(0, 0);
  for (int t = 0; t < nt; ++t) {
    __syncthreads();
    if (t + 1 < nt) stage((t + 1) & 1, (t + 1) * 32);
    compute(t & 1);
  }

  // ---- epilogue: bias, LN stats, residual, write ----
  float bcol[6];
#pragma unroll
  for (int j = 0; j < 6; j++) bcol[j] = bias[wn4 * 96 + j * 16 + lr];
#pragma unroll
  for (int i = 0; i < 4; i++)
#pragma unroll
    for (int j = 0; j < 6; j++)
#pragma unroll
      for (int r = 0; r < 4; r++) acc[i][j][r] += bcol[j];

  // partial sums per row over this wave's 96 cols (alias As[0]: last compute
  // read buf 1, so As[0] region is dead for all waves)
  float* psum = (float*)(&As[0][0]);     // [4][128]
  float* psq  = (float*)(&As[0][1024]);  // [4][128]
#pragma unroll
  for (int i = 0; i < 4; i++)
#pragma unroll
    for (int r = 0; r < 4; r++) {
      float s1 = 0.f, s2 = 0.f;
#pragma unroll
      for (int j = 0; j < 6; j++) {
        float v = acc[i][j][r];
        s1 += v;
        s2 += v * v;
      }
#pragma unroll
      for (int d = 1; d < 16; d <<= 1) {
        s1 += __shfl_xor(s1, d, 64);
        s2 += __shfl_xor(s2, d, 64);
      }
      if (lr == 0) {
        int row = wm2 + i * 16 + lg * 4 + r;
        psum[wn4 * 128 + row] = s1;
        psq[wn4 * 128 + row] = s2;
      }
    }
  __syncthreads();

  float wcol[6], b2col[6];
#pragma unroll
  for (int j = 0; j < 6; j++) {
    int col = wn4 * 96 + j * 16 + lr;
    wcol[j] = nw[col];
    b2col[j] = nb[col];
  }
#pragma unroll
  for (int i = 0; i < 4; i++)
#pragma unroll
    for (int r = 0; r < 4; r++) {
      int row = wm2 + i * 16 + lg * 4 + r;
      float sum = psum[row] + psum[128 + row] + psum[256 + row] + psum[384 + row];
      float sq = psq[row] + psq[128 + row] + psq[256 + row] + psq[384 + row];
      float mu = sum * (1.f / 384.f);
      float rstd = rsqrtf(sq * (1.f / 384.f) - mu * mu + 1e-5f);
      size_t nbase;
      if (MODE == 0) {
        int mrow = m0 + row;
        int bb = mrow >> 12, widx = (mrow >> 6) & 63, tt = mrow & 63;
        int yy = (((widx >> 3) << 3) + (tt >> 3) + 4) & 63;
        int xx = (((widx & 7) << 3) + (tt & 7) + 4) & 63;
        nbase = (size_t)((bb << 12) | (yy << 6) | xx) * 384;
      } else {
        nbase = (size_t)(m0 + row) * 384;
      }
#pragma unroll
      for (int j = 0; j < 6; j++) {
        int col = wn4 * 96 + j * 16 + lr;
        float v = (acc[i][j][r] - mu) * rstd * wcol[j] + b2col[j];
        if (MODE == 0) {
          outb[nbase + col] = f2bf(resf[nbase + col] + v);
        } else {
          outf[nbase + col] = bf2f(resb[nbase + col]) + v;
        }
      }
    }
}

// ---------------------------------------------------------------------------
// shift + window gather + fp32->bf16
// ---------------------------------------------------------------------------
__global__ __launch_bounds__(256) void gather_cvt(
    const float* __restrict__ x, unsigned short* __restrict__ xb) {
  int wv = threadIdx.x >> 6, l = threadIdx.x & 63;
  int m = blockIdx.x * 4 + wv;
  int w = m >> 6, t = m & 63;
  int b = w >> 6, wy = (w >> 3) & 7, wx = w & 7;
  int oy = (wy * 8 + (t >> 3) + 4) & 63;
  int ox = (wx * 8 + (t & 7) + 4) & 63;
  const float2* src =
      (const float2*)(x + (size_t)((((b << 6) | oy) << 6) | ox) * 384 + l * 6);
  float2 f0 = src[0], f1 = src[1], f2 = src[2];
  unsigned* dst = (unsigned*)(xb + (size_t)m * 384 + l * 6);
  dst[0] = pk2(f0.x, f0.y);
  dst[1] = pk2(f1.x, f1.y);
  dst[2] = pk2(f2.x, f2.y);
}

// ---------------------------------------------------------------------------
// Attention: 4 waves/block, wave = one head (unchanged from round 5).
// ---------------------------------------------------------------------------
__global__ __launch_bounds__(256, 4) void attn_win(
    const unsigned short* __restrict__ qkv, const float* __restrict__ btab2,
    const float* __restrict__ lscale, unsigned short* __restrict__ aout) {
  __shared__ __align__(16) unsigned short vT[4][32 * 72];
  __shared__ __align__(16) float rnk[4][64];
  const int w = blockIdx.x;
  const int wv = threadIdx.x >> 6, l = threadIdx.x & 63;
  const int h = blockIdx.y * 4 + wv;
  const int lr = l & 15, lg = l >> 4;
  const size_t base = (size_t)w * 64 * 1152 + h * 32;
  const f32x4 z4 = {0.f, 0.f, 0.f, 0.f};

  {
    const u32x4* vp = (const u32x4*)(qkv + base + (size_t)l * 1152 + 768);
#pragma unroll
    for (int c4 = 0; c4 < 4; c4++) {
      u32x4 c = vp[c4];
#pragma unroll
      for (int e = 0; e < 4; e++) {
        vT[wv][(c4 * 8 + e * 2) * 72 + l] = (unsigned short)(c[e] & 0xffffu);
        vT[wv][(c4 * 8 + e * 2 + 1) * 72 + l] = (unsigned short)(c[e] >> 16);
      }
    }
  }
  u32x4 kf[4];
#pragma unroll
  for (int tj = 0; tj < 4; tj++) {
    kf[tj] = *(const u32x4*)(qkv + base + (size_t)(tj * 16 + lr) * 1152 + 384 + lg * 8);
    float s = ssq8(kf[tj]);
    s += __shfl_xor(s, 16, 64);
    s += __shfl_xor(s, 32, 64);
    if (lg == 0) rnk[wv][tj * 16 + lr] = rsqrtf(fmaxf(s, 1e-24f));
  }
  u32x4 qf[4];
  float rnq[4];
#pragma unroll
  for (int ti = 0; ti < 4; ti++) {
    qf[ti] = *(const u32x4*)(qkv + base + (size_t)(ti * 16 + lr) * 1152 + lg * 8);
    float s = ssq8(qf[ti]);
    s += __shfl_xor(s, 16, 64);
    s += __shfl_xor(s, 32, 64);
    rnq[ti] = rsqrtf(fmaxf(s, 1e-24f));
  }
  __syncthreads();

  u32x4 vb[2][2];
#pragma unroll
  for (int kc = 0; kc < 2; kc++)
#pragma unroll
    for (int tj2 = 0; tj2 < 2; tj2++)
      vb[kc][tj2] = *(const u32x4*)(&vT[wv][(tj2 * 16 + lr) * 72 + kc * 32 + lg * 8]);

  const float scl2 = expf(fminf(lscale[h], 4.6051702f)) * 1.44269504f;
  const int wt = ((((w >> 3) & 7) == 7) ? 2 : 0) | (((w & 7) == 7) ? 1 : 0);
  const float* tabh = btab2 + (((size_t)wt * 12 + h) << 12);
  const int s0l = lr + ((l & 16) ? 32 : 0);
  const int s1l = s0l + 16;
  const bool hi = (l & 32) != 0;

#pragma unroll
  for (int ti = 0; ti < 4; ti++) {
    f32x4 sv[4];
#pragma unroll
    for (int tj = 0; tj < 4; tj++) sv[tj] = mfma16(kf[tj], qf[ti], z4);
    const float* tab = tabh + ((ti * 16 + lr) << 6);
    const float cb = rnq[ti] * scl2;
    f32x4 val[4];
    float m = -1e30f;
#pragma unroll
    for (int tj = 0; tj < 4; tj++) {
      f32x4 rk4 = *(const f32x4*)(&rnk[wv][tj * 16 + lg * 4]);
      f32x4 t4 = *(const f32x4*)(tab + tj * 16 + lg * 4);
#pragma unroll
      for (int r = 0; r < 4; r++) {
        float v = sv[tj][r] * (cb * rk4[r]) + t4[r];
        val[tj][r] = v;
        m = fmaxf(m, v);
      }
    }
    m = fmaxf(m, __shfl_xor(m, 16, 64));
    m = fmaxf(m, __shfl_xor(m, 32, 64));
    float den = 0.f;
#pragma unroll
    for (int tj = 0; tj < 4; tj++)
#pragma unroll
      for (int r = 0; r < 4; r++) {
        float p = fexp2(val[tj][r] - m);
        val[tj][r] = p;
        den += p;
      }
    den += __shfl_xor(den, 16, 64);
    den += __shfl_xor(den, 32, 64);
    float rden = 1.f / den;
#pragma unroll
    for (int tj = 0; tj < 4; tj++)
#pragma unroll
      for (int r = 0; r < 4; r++) val[tj][r] *= rden;

    f32x4 o[2] = {z4, z4};
#pragma unroll
    for (int kc = 0; kc < 2; kc++) {
      unsigned yA0 = cvtpk(val[2 * kc][0], val[2 * kc][1]);
      unsigned yA1 = cvtpk(val[2 * kc][2], val[2 * kc][3]);
      unsigned yB0 = cvtpk(val[2 * kc + 1][0], val[2 * kc + 1][1]);
      unsigned yB1 = cvtpk(val[2 * kc + 1][2], val[2 * kc + 1][3]);
      unsigned a0 = __shfl((int)yA0, s0l, 64), b0 = __shfl((int)yB0, s0l, 64);
      unsigned a1 = __shfl((int)yA1, s0l, 64), b1 = __shfl((int)yB1, s0l, 64);
      unsigned a2 = __shfl((int)yA0, s1l, 64), b2 = __shfl((int)yB0, s1l, 64);
      unsigned a3 = __shfl((int)yA1, s1l, 64), b3 = __shfl((int)yB1, s1l, 64);
      u32x4 pa = {hi ? b0 : a0, hi ? b1 : a1, hi ? b2 : a2, hi ? b3 : a3};
#pragma unroll
      for (int tj2 = 0; tj2 < 2; tj2++) o[tj2] = mfma16(pa, vb[kc][tj2], o[tj2]);
    }
#pragma unroll
    for (int tj2 = 0; tj2 < 2; tj2++)
#pragma unroll
      for (int r = 0; r < 4; r++)
        aout[(size_t)(w * 64 + ti * 16 + lg * 4 + r) * 384 + h * 32 + tj2 * 16 + lr] =
            f2bf(o[tj2][r]);
  }
}

// combined (bias + mask)*log2e table: btab2[wtype][h][q][k]
__global__ __launch_bounds__(256) void btab2_kernel(
    const float* __restrict__ w1, const float* __restrict__ b1,
    const float* __restrict__ w2, const float* __restrict__ b2,
    float* __restrict__ btab2) {
  int p = blockIdx.x * 256 + threadIdx.x;
  int i = p >> 6, j = p & 63;
  float dy = (float)((i >> 3) - (j >> 3));
  float dx = (float)((i & 7) - (j & 7));
  float r0 = (dy > 0.f ? 1.f : (dy < 0.f ? -1.f : 0.f)) * log1pf(fabsf(dy));
  float r1 = (dx > 0.f ? 1.f : (dx < 0.f ? -1.f : 0.f)) * log1pf(fabsf(dx));
  float acc[12];
#pragma unroll
  for (int hh = 0; hh < 12; hh++) acc[hh] = b2[hh];
  for (int c = 0; c < 384; c++) {
    float hv = w1[c * 2] * r0 + w1[c * 2 + 1] * r1 + b1[c];
    hv = fmaxf(hv, 0.f);
#pragma unroll
    for (int hh = 0; hh < 12; hh++) acc[hh] += hv * w2[hh * 384 + c];
  }
  bool ddy = ((i >> 3) >= 4) != ((j >> 3) >= 4);
  bool ddx = ((i & 7) >= 4) != ((j & 7) >= 4);
  const float L2E = 1.44269504f;
#pragma unroll
  for (int wt = 0; wt < 4; wt++) {
    float mask = ((((wt >> 1) != 0) && ddy) || (((wt & 1) != 0) && ddx)) ? -100.f : 0.f;
#pragma unroll
    for (int hh = 0; hh < 12; hh++)
      btab2[(((size_t)wt * 12 + hh) << 12) + p] = (acc[hh] + mask) * L2E;
  }
}

__global__ __launch_bounds__(256) void cvt_kernel(
    const float* __restrict__ s, unsigned short* __restrict__ d, int n) {
  int i = blockIdx.x * 256 + threadIdx.x;
  if (i < n) d[i] = f2bf(s[i]);
}

// ---------------------------------------------------------------------------
extern "C" void kernel_launch(void* const* d_in, const int* in_sizes, int n_in,
                              void* d_out, int out_size, void* d_ws,
                              size_t ws_size, hipStream_t stream) {
  (void)in_sizes; (void)n_in; (void)out_size; (void)ws_size;
  const float* x      = (const float*)d_in[0];
  const float* qkv_w  = (const float*)d_in[1];
  const float* qkv_b  = (const float*)d_in[2];
  const float* proj_w = (const float*)d_in[3];
  const float* proj_b = (const float*)d_in[4];
  const float* mw1    = (const float*)d_in[5];
  const float* mb1    = (const float*)d_in[6];
  const float* mw2    = (const float*)d_in[7];
  const float* mb2    = (const float*)d_in[8];
  const float* lsc    = (const float*)d_in[9];
  const float* n1w    = (const float*)d_in[10];
  const float* n1b    = (const float*)d_in[11];
  const float* w1     = (const float*)d_in[12];
  const float* b1     = (const float*)d_in[13];
  const float* w2     = (const float*)d_in[14];
  const float* b2     = (const float*)d_in[15];
  const float* n2w    = (const float*)d_in[16];
  const float* n2b    = (const float*)d_in[17];

  char* ws = (char*)d_ws;
  unsigned short* wqb  = (unsigned short*)(ws + 0);
  unsigned short* wpb  = (unsigned short*)(ws + 884736);
  unsigned short* w1b  = (unsigned short*)(ws + 1179648);
  unsigned short* w2b  = (unsigned short*)(ws + 2359296);
  float* btab2         = (float*)(ws + 3538944);             // 786 KB
  unsigned short* xb   = (unsigned short*)(ws + 4718592);    // 100.7 MB
  unsigned short* qkvb = (unsigned short*)(ws + 105381888);  // 302 MB
  unsigned short* att  = (unsigned short*)(ws + 407371776);  // 100.7 MB
  unsigned short* hb   = (unsigned short*)(ws + 508035072);  // 100.7 MB (chunk)
  unsigned short* y1b  = xb;  // xb dead after QKV GEMM; NOT aliased with att
  float* yout = (float*)d_out;

  cvt_kernel<<<dim3(1728), 256, 0, stream>>>(qkv_w, wqb, 442368);
  cvt_kernel<<<dim3(576), 256, 0, stream>>>(proj_w, wpb, 147456);
  cvt_kernel<<<dim3(2304), 256, 0, stream>>>(w1, w1b, 589824);
  cvt_kernel<<<dim3(2304), 256, 0, stream>>>(w2, w2b, 589824);
  btab2_kernel<<<dim3(16), 256, 0, stream>>>(mw1, mb1, mw2, mb2, btab2);
  gather_cvt<<<dim3(32768), 256, 0, stream>>>(x, xb);

  // QKV: 131072 x 1152 x 384
  gemm_lds<0><<<dim3(9216), 256, 0, stream>>>(xb, wqb, qkv_b, qkvb, 1152, 384, 9);
  // attention: 4 heads/block
  attn_win<<<dim3(2048, 3), 256, 0, stream>>>(qkvb, btab2, lsc, att);
  // proj + LN1 + residual fused: att -> y1b (bf16, ungathered order)
  gemm_ln<0><<<dim3(1024), 512, 0, stream>>>(
      att, wpb, proj_b, x, nullptr, n1w, n1b, y1b, nullptr, 384);
  // MLP, 4 chunks of 32768 rows; fc2 + LN2 + residual fused -> yout
  for (int c = 0; c < 4; c++) {
    const unsigned short* ya = y1b + (size_t)c * 32768 * 384;
    float* yc = yout + (size_t)c * 32768 * 384;
    gemm_lds<1><<<dim3(3072), 256, 0, stream>>>(ya, w1b, b1, hb, 1536, 384, 12);
    gemm_ln<1><<<dim3(256), 512, 0, stream>>>(
        hb, w2b, b2, nullptr, ya, n2w, n2b, nullptr, yc, 1536);
  }
}